// Round 3
// baseline (140.504 us; speedup 1.0000x reference)
//
#include <hip/hip_runtime.h>

typedef float f32x4 __attribute__((ext_vector_type(4)));
typedef __bf16 bf16x8 __attribute__((ext_vector_type(8)));
typedef __bf16 bf16x4 __attribute__((ext_vector_type(4)));
typedef short short4v __attribute__((ext_vector_type(4)));

#define MFMA32K(a, b, c) __builtin_amdgcn_mfma_f32_16x16x32_bf16((a), (b), (c), 0, 0, 0)
#define MFMA16K(a, b, c) __builtin_amdgcn_mfma_f32_16x16x16bf16_1k((a), (b), (c), 0, 0, 0)
#define CFENCE() asm volatile("" ::: "memory")
#define DSFENCE() asm volatile("s_waitcnt lgkmcnt(0)" ::: "memory")

constexpr int Bn = 4, Tn = 4096, Cn = 512, Hn = 64;
// fold C^-0.5 (reference scales by n_embed^-0.5) and log2(e) into Wq.
constexpr float QSCALE = 1.4426950408889634f * 0.04419417382415922f;
constexpr float M0 = -30000.0f;  // finite sentinel: exp2(masked - M0) == 0, never exp2(0)

// ---------------- kernel 0: W fp32 -> bf16 (Wq pre-scaled) ----------------
__global__ void wconv(const float* __restrict__ Wq, const float* __restrict__ Wk,
                      const float* __restrict__ Wv, __bf16* __restrict__ Wb) {
    int t = blockIdx.y;
    int i = blockIdx.x * 256 + threadIdx.x;
    const float* src = (t == 0) ? Wq : (t == 1) ? Wk : Wv;
    float scale = (t == 0) ? QSCALE : 1.0f;
    Wb[t * Hn * Cn + i] = (__bf16)(src[i] * scale);
}

__device__ inline bf16x8 cvt8(float4 u0, float4 u1) {
    bf16x8 r;
    r[0] = (__bf16)u0.x; r[1] = (__bf16)u0.y; r[2] = (__bf16)u0.z; r[3] = (__bf16)u0.w;
    r[4] = (__bf16)u1.x; r[5] = (__bf16)u1.y; r[6] = (__bf16)u1.z; r[7] = (__bf16)u1.w;
    return r;
}

// ---------------- kernel 1: fused QKV projection, split-K x2 ---------------
// 8 waves/block: 4 row-groups x 2 K-halves -> 2048 waves (2/SIMD).
__global__ __launch_bounds__(512) void proj(const float* __restrict__ x,
                                            const __bf16* __restrict__ Wb,
                                            __bf16* __restrict__ Qb,
                                            __bf16* __restrict__ Kb,
                                            __bf16* __restrict__ VT) {
    const int tid = threadIdx.x;
    const int lane = tid & 63, wid = tid >> 6;
    const int rg = wid >> 1, kh = wid & 1;
    const int c = lane & 15, h = lane >> 4;
    const int row0 = blockIdx.x * 64 + rg * 16;

    f32x4 acc[3][4] = {};
    const float* xr = x + (size_t)(row0 + c) * Cn + kh * 256;

#pragma unroll
    for (int ks = 0; ks < 8; ++ks) {
        const int kb = ks * 32 + 8 * h;
        const float4* p0 = (const float4*)(xr + kb);
        bf16x8 a0 = cvt8(p0[0], p0[1]);
#pragma unroll
        for (int w = 0; w < 3; ++w)
#pragma unroll
            for (int nt = 0; nt < 4; ++nt) {
                bf16x8 bf = *(const bf16x8*)(Wb + (size_t)(w * Hn + nt * 16 + c) * Cn + kh * 256 + kb);
                acc[w][nt] = MFMA32K(a0, bf, acc[w][nt]);
            }
    }

    __shared__ float ml[4][64][52];      // split-K partials (f32)
    __shared__ __bf16 tb[4][16][72];     // transpose buffer

    if (kh) {
#pragma unroll
        for (int w = 0; w < 3; ++w)
#pragma unroll
            for (int nt = 0; nt < 4; ++nt)
                *(f32x4*)&ml[rg][lane][(w * 4 + nt) * 4] = acc[w][nt];
    }
    __syncthreads();
    if (!kh) {
#pragma unroll
        for (int w = 0; w < 3; ++w)
#pragma unroll
            for (int nt = 0; nt < 4; ++nt)
                acc[w][nt] += *(const f32x4*)&ml[rg][lane][(w * 4 + nt) * 4];

        // Q, K epilogue: per-wave LDS transpose -> coalesced row-major stores.
#pragma unroll
        for (int w = 0; w < 2; ++w) {
            CFENCE();
#pragma unroll
            for (int nt = 0; nt < 4; ++nt)
#pragma unroll
                for (int r = 0; r < 4; ++r)
                    tb[rg][h * 4 + r][nt * 16 + c] = (__bf16)acc[w][nt][r];
            DSFENCE();
            __bf16* dst = (w == 0) ? Qb : Kb;
#pragma unroll
            for (int ch = 0; ch < 2; ++ch) {
                int rr = ch * 8 + (lane >> 3);
                bf16x8 vv = *(const bf16x8*)(&tb[rg][rr][(lane & 7) * 8]);
                *(bf16x8*)(dst + (size_t)(row0 + rr) * Hn + (lane & 7) * 8) = vv;
            }
            CFENCE();
        }

        // V epilogue: direct transposed store.
        const int b = row0 >> 12;
        const int t0 = row0 & (Tn - 1);
#pragma unroll
        for (int nt = 0; nt < 4; ++nt) {
            f32x4 a = acc[2][nt];
            bf16x4 v4;
            v4[0] = (__bf16)a.x; v4[1] = (__bf16)a.y;
            v4[2] = (__bf16)a.z; v4[3] = (__bf16)a.w;
            *(bf16x4*)(VT + (size_t)(b * Hn + nt * 16 + c) * Tn + t0 + h * 4) = v4;
        }
    }
}

// ---------------- kernel 2: causal flash attention -------------------------
// 256 threads = 4 waves, each one KV-split of a 16-row q-tile. Swapped QK^T:
// lane owns q-row c -> scalar m/l, zero LDS/shuffles in the inner loop.
__global__ __launch_bounds__(256) void attn(const __bf16* __restrict__ Qb,
                                            const __bf16* __restrict__ Kb,
                                            const __bf16* __restrict__ VT,
                                            float* __restrict__ out) {
    const int tid = threadIdx.x;
    const int lane = tid & 63, ws = tid >> 6;
    const int c = lane & 15, h = lane >> 4;
    const int qt = (Tn / 16 - 1) - (int)(blockIdx.x >> 2);  // LPT
    const int b = blockIdx.x & 3;                           // one batch per XCD
    const int qbase = qt * 16;

    const __bf16* Kbase = Kb + (size_t)b * Tn * Hn;
    const __bf16* Vbase = VT + (size_t)b * Hn * Tn;

    const size_t qrow = (size_t)b * Tn + qbase + c;
    const bf16x8 qf0 = *(const bf16x8*)(Qb + qrow * Hn + 8 * h);
    const bf16x8 qf1 = *(const bf16x8*)(Qb + qrow * Hn + 32 + 8 * h);

    f32x4 o[4] = {};
    float m = M0, l = 0.0f;

    const int nkv = (qbase + 15) / 64 + 1;

    // K fragment prefetch (one tile ahead), clamped in-bounds.
    bf16x8 kf[4][2];
    {
        const int ktc = (ws < nkv) ? ws : nkv - 1;
#pragma unroll
        for (int ct = 0; ct < 4; ++ct) {
            const __bf16* kp = Kbase + (size_t)(ktc * 64 + ct * 16 + c) * Hn;
            kf[ct][0] = *(const bf16x8*)(kp + 8 * h);
            kf[ct][1] = *(const bf16x8*)(kp + 32 + 8 * h);
        }
    }

    for (int kt = ws; kt < nkv; kt += 4) {
        const int j0 = kt * 64;
        // S^T = K Q^T : lane (c,h) reg (ct,r) = S[q=c][kv=j0+16ct+4h+r]
        f32x4 s[4];
#pragma unroll
        for (int ct = 0; ct < 4; ++ct) {
            f32x4 z = {};
            z = MFMA32K(kf[ct][0], qf0, z);
            z = MFMA32K(kf[ct][1], qf1, z);
            s[ct] = z;
        }
        // V fragments for this tile (consumed at PV; latency hides under softmax)
        short4v vf[4][4];
#pragma unroll
        for (int dt = 0; dt < 4; ++dt)
#pragma unroll
            for (int ct = 0; ct < 4; ++ct)
                vf[dt][ct] = *(const short4v*)(Vbase + (size_t)(dt * 16 + c) * Tn + j0 + ct * 16 + 4 * h);
        // prefetch next K tile
        {
            const int ktn = (kt + 4 < nkv) ? kt + 4 : kt;
#pragma unroll
            for (int ct = 0; ct < 4; ++ct) {
                const __bf16* kp = Kbase + (size_t)(ktn * 64 + ct * 16 + c) * Hn;
                kf[ct][0] = *(const bf16x8*)(kp + 8 * h);
                kf[ct][1] = *(const bf16x8*)(kp + 32 + 8 * h);
            }
        }
        // causal mask (diagonal tiles only; per-lane, in-register)
        if (j0 + 63 > qbase) {
#pragma unroll
            for (int ct = 0; ct < 4; ++ct)
#pragma unroll
                for (int r = 0; r < 4; ++r)
                    if (j0 + ct * 16 + 4 * h + r > qbase + c) s[ct][r] = -1e30f;
        }
        // defer-max online softmax (T13): common path has NO reduction.
        float lm = fmaxf(fmaxf(fmaxf(s[0][0], s[0][1]), fmaxf(s[0][2], s[0][3])),
                         fmaxf(fmaxf(s[1][0], s[1][1]), fmaxf(s[1][2], s[1][3])));
        lm = fmaxf(lm, fmaxf(fmaxf(fmaxf(s[2][0], s[2][1]), fmaxf(s[2][2], s[2][3])),
                             fmaxf(fmaxf(s[3][0], s[3][1]), fmaxf(s[3][2], s[3][3]))));
        if (!__all(lm <= m + 8.0f)) {
            float rm = lm;
            rm = fmaxf(rm, __shfl_xor(rm, 16));
            rm = fmaxf(rm, __shfl_xor(rm, 32));  // row max, uniform across h
            float mn = fmaxf(m, rm);
            float sc = __builtin_amdgcn_exp2f(m - mn);
            m = mn;
            l *= sc;
#pragma unroll
            for (int dt = 0; dt < 4; ++dt) o[dt] *= sc;
        }
        // P = exp2(S - m), per-lane row sum, pack to bf16 B-fragments (K=16)
        short4v pf[4];
        float ls = 0.0f;
#pragma unroll
        for (int ct = 0; ct < 4; ++ct) {
            bf16x4 pb;
#pragma unroll
            for (int r = 0; r < 4; ++r) {
                float p = __builtin_amdgcn_exp2f(s[ct][r] - m);
                ls += p;
                pb[r] = (__bf16)p;
            }
            pf[ct] = __builtin_bit_cast(short4v, pb);
        }
        l += ls;
        // O^T += V^T P^T : 16x16x16 MFMAs, zero cross-lane movement.
#pragma unroll
        for (int dt = 0; dt < 4; ++dt)
#pragma unroll
            for (int ct = 0; ct < 4; ++ct)
                o[dt] = MFMA16K(vf[dt][ct], pf[ct], o[dt]);
    }

    // finalize per-lane partial l: reduce across the 4 h-lanes of each q-row.
    l += __shfl_xor(l, 16);
    l += __shfl_xor(l, 32);

    __shared__ float Lo[4][16][68];
    __shared__ float Lm[4][16];
    __shared__ float Ll[4][16];
    if (lane < 16) { Lm[ws][c] = m; Ll[ws][c] = l; }
#pragma unroll
    for (int dt = 0; dt < 4; ++dt)
        *(f32x4*)&Lo[ws][c][dt * 16 + 4 * h] = o[dt];
    __syncthreads();

    // merge the 4 KV-split waves; out = O / L (fp32 [B][T][64])
    const int col = tid & 63, rg = tid >> 6;
    float* ob = out + ((size_t)b * Tn + qbase) * Hn;
#pragma unroll
    for (int rr = 0; rr < 4; ++rr) {
        int row = rg * 4 + rr;
        float M = fmaxf(fmaxf(Lm[0][row], Lm[1][row]), fmaxf(Lm[2][row], Lm[3][row]));
        float L = 0.f, O = 0.f;
#pragma unroll
        for (int w = 0; w < 4; ++w) {
            float e = __builtin_amdgcn_exp2f(Lm[w][row] - M);
            L += Ll[w][row] * e;
            O += Lo[w][row][col] * e;
        }
        ob[(size_t)row * Hn + col] = O / L;
    }
}

// ---------------- launcher -------------------------------------------------
extern "C" void kernel_launch(void* const* d_in, const int* in_sizes, int n_in,
                              void* d_out, int out_size, void* d_ws, size_t ws_size,
                              hipStream_t stream) {
    const float* x  = (const float*)d_in[0];
    const float* Wq = (const float*)d_in[1];
    const float* Wk = (const float*)d_in[2];
    const float* Wv = (const float*)d_in[3];
    float* out = (float*)d_out;

    char* ws = (char*)d_ws;
    __bf16* Wb = (__bf16*)ws;                                  // 196608 B
    __bf16* Qb = (__bf16*)(ws + 196608);                       // 2097152 B
    __bf16* Kb = (__bf16*)(ws + 196608 + 2097152);             // 2097152 B
    __bf16* VT = (__bf16*)(ws + 196608 + 2 * 2097152);         // 2097152 B

    wconv<<<dim3(128, 3), 256, 0, stream>>>(Wq, Wk, Wv, Wb);
    proj<<<256, 512, 0, stream>>>(x, Wb, Qb, Kb, VT);
    attn<<<1024, 256, 0, stream>>>(Qb, Kb, VT, out);
}

// Round 4
// 55.647 us; speedup vs baseline: 2.5249x; 2.5249x over previous
//
#include <hip/hip_runtime.h>

typedef float f32x4 __attribute__((ext_vector_type(4)));
typedef __bf16 bf16x8 __attribute__((ext_vector_type(8)));
typedef __bf16 bf16x4 __attribute__((ext_vector_type(4)));
typedef short short4v __attribute__((ext_vector_type(4)));

#define MFMA32K(a, b, c) __builtin_amdgcn_mfma_f32_16x16x32_bf16((a), (b), (c), 0, 0, 0)
#define MFMA16K(a, b, c) __builtin_amdgcn_mfma_f32_16x16x16bf16_1k((a), (b), (c), 0, 0, 0)
#define CFENCE() asm volatile("" ::: "memory")
#define DSFENCE() asm volatile("s_waitcnt lgkmcnt(0)" ::: "memory")

constexpr int Tn = 4096, Cn = 512, Hn = 64;
// fold C^-0.5 (reference scales by n_embed^-0.5) and log2(e) into Wq.
constexpr float QSCALE = 1.4426950408889634f * 0.04419417382415922f;
constexpr float M0 = -30000.0f;  // finite sentinel; exp2(x - M0) underflows to 0

// ---------------- kernel 0: W fp32 -> bf16 (Wq pre-scaled) ----------------
__global__ void wconv(const float* __restrict__ Wq, const float* __restrict__ Wk,
                      const float* __restrict__ Wv, __bf16* __restrict__ Wb) {
    int t = blockIdx.y;
    int i = blockIdx.x * 256 + threadIdx.x;
    const float* src = (t == 0) ? Wq : (t == 1) ? Wk : Wv;
    float scale = (t == 0) ? QSCALE : 1.0f;
    Wb[t * Hn * Cn + i] = (__bf16)(src[i] * scale);
}

__device__ inline bf16x8 cvt8(float4 u0, float4 u1) {
    bf16x8 r;
    r[0] = (__bf16)u0.x; r[1] = (__bf16)u0.y; r[2] = (__bf16)u0.z; r[3] = (__bf16)u0.w;
    r[4] = (__bf16)u1.x; r[5] = (__bf16)u1.y; r[6] = (__bf16)u1.z; r[7] = (__bf16)u1.w;
    return r;
}

// ---------------- kernel 1: QKV projection, W k-slices staged in LDS -------
// 256 blocks x 4 waves x 16 rows. W slice (192x32 bf16 = 12KB) double-buffered,
// issue-early/write-late staging (T14); x streamed once from HBM.
__global__ __launch_bounds__(256) void proj(const float* __restrict__ x,
                                            const __bf16* __restrict__ Wb,
                                            __bf16* __restrict__ Qb,
                                            __bf16* __restrict__ Kb,
                                            __bf16* __restrict__ VF) {
    const int tid = threadIdx.x;
    const int lane = tid & 63, wid = tid >> 6;
    const int c = lane & 15, h = lane >> 4;
    const int row0 = blockIdx.x * 64 + wid * 16;

    __shared__ __bf16 Ws[2][192 * 36];   // padded rows: 36 elems (72B)
    __shared__ __bf16 tb[4][16][72];     // per-wave transpose buffer

    f32x4 acc[3][4] = {};
    const float* xr = x + (size_t)(row0 + c) * Cn;

    // stage slice 0 (synchronous, once)
#pragma unroll
    for (int i = 0; i < 3; ++i) {
        int g = tid + i * 256, r = g >> 2, gc = g & 3;
        *(bf16x8*)&Ws[0][r * 36 + gc * 8] = *(const bf16x8*)(Wb + (size_t)r * Cn + gc * 8);
    }
    float4 xc0 = *(const float4*)(xr + 8 * h);
    float4 xc1 = *(const float4*)(xr + 8 * h + 4);
    __syncthreads();

#pragma unroll 2
    for (int ks = 0; ks < 16; ++ks) {
        const int cur = ks & 1;
        bf16x8 wreg[3];
        float4 xn0, xn1;
        if (ks < 15) {  // issue next-slice loads early (global -> reg)
#pragma unroll
            for (int i = 0; i < 3; ++i) {
                int g = tid + i * 256, r = g >> 2, gc = g & 3;
                wreg[i] = *(const bf16x8*)(Wb + (size_t)r * Cn + (ks + 1) * 32 + gc * 8);
            }
            xn0 = *(const float4*)(xr + (ks + 1) * 32 + 8 * h);
            xn1 = *(const float4*)(xr + (ks + 1) * 32 + 8 * h + 4);
        }
        bf16x8 a0 = cvt8(xc0, xc1);
#pragma unroll
        for (int w = 0; w < 3; ++w)
#pragma unroll
            for (int nt = 0; nt < 4; ++nt) {
                bf16x8 bf = *(const bf16x8*)&Ws[cur][(w * 64 + nt * 16 + c) * 36 + 8 * h];
                acc[w][nt] = MFMA32K(a0, bf, acc[w][nt]);
            }
        if (ks < 15) {  // write-late: ds_write after compute
#pragma unroll
            for (int i = 0; i < 3; ++i) {
                int g = tid + i * 256, r = g >> 2, gc = g & 3;
                *(bf16x8*)&Ws[cur ^ 1][r * 36 + gc * 8] = wreg[i];
            }
            xc0 = xn0; xc1 = xn1;
        }
        __syncthreads();
    }

    // Q, K epilogue: per-wave LDS transpose -> coalesced row-major stores.
#pragma unroll
    for (int w = 0; w < 2; ++w) {
        CFENCE();
#pragma unroll
        for (int nt = 0; nt < 4; ++nt)
#pragma unroll
            for (int r = 0; r < 4; ++r)
                tb[wid][h * 4 + r][nt * 16 + c] = (__bf16)acc[w][nt][r];
        DSFENCE();
        __bf16* dst = (w == 0) ? Qb : Kb;
#pragma unroll
        for (int ch = 0; ch < 2; ++ch) {
            int rr = ch * 8 + (lane >> 3);
            bf16x8 vv = *(const bf16x8*)(&tb[wid][rr][(lane & 7) * 8]);
            *(bf16x8*)(dst + (size_t)(row0 + rr) * Hn + (lane & 7) * 8) = vv;
        }
        CFENCE();
    }

    // V epilogue -> fragment-major VF[b][tile][h][d][4]:
    // lane holds V[token=t0+4h+r][d=16nt+c] = acc[2][nt][r].
    const int b = row0 >> 12;
    const int t0 = row0 & (Tn - 1);
    const int tile = t0 >> 4;
#pragma unroll
    for (int nt = 0; nt < 4; ++nt) {
        f32x4 a = acc[2][nt];
        bf16x4 v4;
        v4[0] = (__bf16)a.x; v4[1] = (__bf16)a.y;
        v4[2] = (__bf16)a.z; v4[3] = (__bf16)a.w;
        size_t off = ((size_t)((b * 256 + tile) * 4 + h) * 64 + (nt * 16 + c)) * 4;
        *(bf16x4*)(VF + off) = v4;
    }
}

// ---------------- kernel 2: causal flash attention -------------------------
// 256 blocks (1/CU) x 8 waves. Block = 64 q-rows (4 subtiles/wave), 8-way
// kv-split. In-register K/V (L2-resident, coalesced), zero LDS in inner loop;
// tree-merge of the 8 kv-split partials at the end.
__global__ __launch_bounds__(512) void attn(const __bf16* __restrict__ Qb,
                                            const __bf16* __restrict__ Kb,
                                            const __bf16* __restrict__ VF,
                                            float* __restrict__ out) {
    const int tid = threadIdx.x;
    const int lane = tid & 63, ks = tid >> 6;
    const int c = lane & 15, h = lane >> 4;
    const int g = 63 - (int)(blockIdx.x >> 2);   // LPT: longest q-group first
    const int b = blockIdx.x & 3;
    const int qbase = g * 64;

    const __bf16* Kbase = Kb + (size_t)b * Tn * Hn;
    const __bf16* Vbase = VF + (size_t)b * 256 * 1024;

    // Q fragments for 4 subtiles (held in regs for the whole kernel)
    bf16x8 qf[4][2];
#pragma unroll
    for (int qs = 0; qs < 4; ++qs) {
        const __bf16* qp = Qb + (size_t)(b * Tn + qbase + qs * 16 + c) * Hn;
        qf[qs][0] = *(const bf16x8*)(qp + 8 * h);
        qf[qs][1] = *(const bf16x8*)(qp + 32 + 8 * h);
    }

    f32x4 o[4][4] = {};
    float m[4] = {M0, M0, M0, M0};
    float l[4] = {};

    const int nkv = g + 1;

    for (int kt = ks; kt < nkv; kt += 8) {
        const int j0 = kt * 64;
        // V fragments: fragment-major -> fully coalesced 8B loads
        short4v vf[4][4];
        const __bf16* vt = Vbase + ((size_t)(j0 >> 4) << 10) + (h << 8);
#pragma unroll
        for (int dt = 0; dt < 4; ++dt)
#pragma unroll
            for (int ct = 0; ct < 4; ++ct)
                vf[dt][ct] = *(const short4v*)(vt + (ct << 10) + ((dt * 16 + c) << 2));
        // K fragments (row-major, full-line reads)
        bf16x8 kf[4][2];
#pragma unroll
        for (int ct = 0; ct < 4; ++ct) {
            const __bf16* kp = Kbase + (size_t)(j0 + ct * 16 + c) * Hn;
            kf[ct][0] = *(const bf16x8*)(kp + 8 * h);
            kf[ct][1] = *(const bf16x8*)(kp + 32 + 8 * h);
        }
        const bool diag = (kt == g);

#pragma unroll
        for (int qs = 0; qs < 4; ++qs) {
            // S^T = K Q^T : lane holds S[q=c][kv=j0+16ct+4h+r]
            f32x4 s[4];
#pragma unroll
            for (int ct = 0; ct < 4; ++ct) {
                f32x4 z = {};
                z = MFMA32K(kf[ct][0], qf[qs][0], z);
                z = MFMA32K(kf[ct][1], qf[qs][1], z);
                s[ct] = z;
            }
            if (diag) {
#pragma unroll
                for (int ct = 0; ct < 4; ++ct)
#pragma unroll
                    for (int r = 0; r < 4; ++r)
                        if (j0 + ct * 16 + 4 * h + r > qbase + qs * 16 + c)
                            s[ct][r] = -1e30f;
            }
            // defer-max online softmax
            float lm = fmaxf(fmaxf(fmaxf(s[0][0], s[0][1]), fmaxf(s[0][2], s[0][3])),
                             fmaxf(fmaxf(s[1][0], s[1][1]), fmaxf(s[1][2], s[1][3])));
            lm = fmaxf(lm, fmaxf(fmaxf(fmaxf(s[2][0], s[2][1]), fmaxf(s[2][2], s[2][3])),
                                 fmaxf(fmaxf(s[3][0], s[3][1]), fmaxf(s[3][2], s[3][3]))));
            if (!__all(lm <= m[qs] + 8.0f)) {
                float rm = fmaxf(lm, __shfl_xor(lm, 16));
                rm = fmaxf(rm, __shfl_xor(rm, 32));
                float mn = fmaxf(m[qs], rm);
                float sc = __builtin_amdgcn_exp2f(m[qs] - mn);
                m[qs] = mn;
                l[qs] *= sc;
#pragma unroll
                for (int dt = 0; dt < 4; ++dt) o[qs][dt] *= sc;
            }
            short4v pf[4];
            float lsum = 0.0f;
#pragma unroll
            for (int ct = 0; ct < 4; ++ct) {
                bf16x4 pb;
#pragma unroll
                for (int r = 0; r < 4; ++r) {
                    float p = __builtin_amdgcn_exp2f(s[ct][r] - m[qs]);
                    lsum += p;
                    pb[r] = (__bf16)p;
                }
                pf[ct] = __builtin_bit_cast(short4v, pb);
            }
            l[qs] += lsum;
            // O^T += V^T P^T
#pragma unroll
            for (int dt = 0; dt < 4; ++dt)
#pragma unroll
                for (int ct = 0; ct < 4; ++ct)
                    o[qs][dt] = MFMA16K(vf[dt][ct], pf[ct], o[qs][dt]);
        }
    }

    // reduce l across the 4 h-lanes of each q-row
#pragma unroll
    for (int qs = 0; qs < 4; ++qs) {
        l[qs] += __shfl_xor(l[qs], 16);
        l[qs] += __shfl_xor(l[qs], 32);
    }

    // -------- tree-merge of the 8 kv-split waves ---------------------------
    __shared__ float Mo[4][64][68];
    __shared__ float Mml[4][64][8];
#pragma unroll
    for (int step = 4; step >= 1; step >>= 1) {
        if (ks >= step && ks < 2 * step) {
            int slot = ks - step;
#pragma unroll
            for (int qs = 0; qs < 4; ++qs) {
                Mml[slot][lane][qs] = m[qs];
                Mml[slot][lane][4 + qs] = l[qs];
#pragma unroll
                for (int dt = 0; dt < 4; ++dt)
                    *(f32x4*)&Mo[slot][lane][(qs * 4 + dt) * 4] = o[qs][dt];
            }
        }
        __syncthreads();
        if (ks < step) {
#pragma unroll
            for (int qs = 0; qs < 4; ++qs) {
                float m2 = Mml[ks][lane][qs];
                float l2 = Mml[ks][lane][4 + qs];
                float M = fmaxf(m[qs], m2);
                float e1 = __builtin_amdgcn_exp2f(m[qs] - M);
                float e2 = __builtin_amdgcn_exp2f(m2 - M);
                m[qs] = M;
                l[qs] = l[qs] * e1 + l2 * e2;
#pragma unroll
                for (int dt = 0; dt < 4; ++dt) {
                    f32x4 o2 = *(const f32x4*)&Mo[ks][lane][(qs * 4 + dt) * 4];
                    o[qs][dt] = o[qs][dt] * e1 + o2 * e2;
                }
            }
        }
        __syncthreads();
    }

    // wave 0 holds the final (m,l,o): out = O / l, fp32 [B][T][64]
    if (ks == 0) {
#pragma unroll
        for (int qs = 0; qs < 4; ++qs) {
            float rl = 1.0f / l[qs];
            float* ob = out + ((size_t)(b * Tn + qbase + qs * 16 + c)) * Hn;
#pragma unroll
            for (int dt = 0; dt < 4; ++dt) {
                f32x4 v = o[qs][dt] * rl;
                *(f32x4*)(ob + dt * 16 + 4 * h) = v;
            }
        }
    }
}

// ---------------- launcher -------------------------------------------------
extern "C" void kernel_launch(void* const* d_in, const int* in_sizes, int n_in,
                              void* d_out, int out_size, void* d_ws, size_t ws_size,
                              hipStream_t stream) {
    const float* x  = (const float*)d_in[0];
    const float* Wq = (const float*)d_in[1];
    const float* Wk = (const float*)d_in[2];
    const float* Wv = (const float*)d_in[3];
    float* out = (float*)d_out;

    char* ws = (char*)d_ws;
    __bf16* Wb = (__bf16*)ws;                                  // 196608 B
    __bf16* Qb = (__bf16*)(ws + 196608);                       // 2097152 B
    __bf16* Kb = (__bf16*)(ws + 196608 + 2097152);             // 2097152 B
    __bf16* VF = (__bf16*)(ws + 196608 + 2 * 2097152);         // 2097152 B

    wconv<<<dim3(128, 3), 256, 0, stream>>>(Wq, Wk, Wv, Wb);
    proj<<<256, 256, 0, stream>>>(x, Wb, Qb, Kb, VF);
    attn<<<256, 512, 0, stream>>>(Qb, Kb, VF, out);
}